// Round 1
// baseline (1022.357 us; speedup 1.0000x reference)
//
#include <hip/hip_runtime.h>
#include <hip/hip_bf16.h>

// Problem constants (from reference setup_inputs)
#define NN   8
#define CIN  128
#define HH   96
#define WW   96
#define COUT 256
#define KK   9      // 3x3
#define HO   96
#define WO   96
#define TPOS 8      // spatial positions per block (96 % 8 == 0 -> same row)

// ---------------------------------------------------------------------------
// Kernel: NCHW -> NHWC transpose of the input image into workspace.
// out[((n*H+y)*W+x)*C + c] = in[((n*C+c)*H+y)*W+x]
// ---------------------------------------------------------------------------
__global__ __launch_bounds__(256) void nchw_to_nhwc(const float* __restrict__ in,
                                                    float* __restrict__ outp) {
    int idx = blockIdx.x * 256 + threadIdx.x;     // over N*H*W*C
    if (idx >= NN * HH * WW * CIN) return;
    int c   = idx & (CIN - 1);
    int sp  = idx >> 7;                            // n*H*W + y*W + x
    int x   = sp % WW;
    int yz  = sp / WW;
    int y   = yz % HH;
    int n   = yz / HH;
    outp[idx] = in[((n * CIN + c) * HH + y) * WW + x];
}

// ---------------------------------------------------------------------------
// Kernel: weight [Cout][Cin][K] -> wT [K][Cin][Cout]
// ---------------------------------------------------------------------------
__global__ __launch_bounds__(256) void w_transpose(const float* __restrict__ w,
                                                   float* __restrict__ wT) {
    int idx = blockIdx.x * 256 + threadIdx.x;     // over K*Cin*Cout = 294912
    if (idx >= KK * CIN * COUT) return;
    int co = idx & (COUT - 1);
    int c  = (idx >> 8) & (CIN - 1);
    int k  = idx >> 15;
    wT[idx] = w[(co * CIN + c) * KK + k];
}

// ---------------------------------------------------------------------------
// Main fused kernel.
// FAST=true : img is NHWC (ws), wgt is wT [K][Cin][Cout]
// FAST=false: img is NCHW (original), wgt is original [Cout][Cin][K]
// Block: 256 threads (thread = one Cout channel), handles TPOS=8 consecutive
// output positions in the same output row. Grid = N*Ho*Wo / TPOS.
// ---------------------------------------------------------------------------
template <bool FAST>
__global__ __launch_bounds__(256) void deform_main(const float* __restrict__ img,
                                                   const float* __restrict__ off,
                                                   const float* __restrict__ wgt,
                                                   float* __restrict__ out) {
    __shared__ float samp[TPOS][CIN];   // 4 KiB

    const int tid = threadIdx.x;        // = co
    const int p0  = blockIdx.x * TPOS;  // linear position base
    const int n   = p0 / (HO * WO);
    const int rem = p0 % (HO * WO);
    const int ho  = rem / WO;
    const int wo0 = rem % WO;           // wo = wo0 + t, all in same row

    float acc[TPOS];
#pragma unroll
    for (int t = 0; t < TPOS; ++t) acc[t] = 0.f;

    for (int k = 0; k < KK; ++k) {
        __syncthreads();   // protect samp from previous iteration's readers
        // ---- stage: bilinear gather of samp[t][c] for this tap ----
        const int kh = k / 3, kw = k % 3;
#pragma unroll
        for (int it = 0; it < (TPOS * CIN) / 256; ++it) {
            int idx = tid + it * 256;
            int t   = idx >> 7;          // 0..7
            int c   = idx & (CIN - 1);   // 0..127
            int wo  = wo0 + t;

            float dy = off[(((size_t)n * 2 * KK + 2 * k) * HO + ho) * WO + wo];
            float dx = off[(((size_t)n * 2 * KK + 2 * k + 1) * HO + ho) * WO + wo];
            float py = (float)(ho - 1 + kh) + dy;
            float px = (float)(wo - 1 + kw) + dx;
            float y0f = floorf(py), x0f = floorf(px);
            float ly = py - y0f, lx = px - x0f;
            int y0 = (int)y0f, x0 = (int)x0f;

            float v00 = 0.f, v01 = 0.f, v10 = 0.f, v11 = 0.f;
            if (FAST) {
                const float* base = img + (size_t)n * HH * WW * CIN + c;
                if ((unsigned)y0 < (unsigned)HH) {
                    const float* row = base + (size_t)y0 * WW * CIN;
                    if ((unsigned)x0 < (unsigned)WW)       v00 = row[(size_t)x0 * CIN];
                    if ((unsigned)(x0 + 1) < (unsigned)WW) v01 = row[(size_t)(x0 + 1) * CIN];
                }
                if ((unsigned)(y0 + 1) < (unsigned)HH) {
                    const float* row = base + (size_t)(y0 + 1) * WW * CIN;
                    if ((unsigned)x0 < (unsigned)WW)       v10 = row[(size_t)x0 * CIN];
                    if ((unsigned)(x0 + 1) < (unsigned)WW) v11 = row[(size_t)(x0 + 1) * CIN];
                }
            } else {
                const float* base = img + ((size_t)n * CIN + c) * HH * WW;
                if ((unsigned)y0 < (unsigned)HH) {
                    const float* row = base + (size_t)y0 * WW;
                    if ((unsigned)x0 < (unsigned)WW)       v00 = row[x0];
                    if ((unsigned)(x0 + 1) < (unsigned)WW) v01 = row[x0 + 1];
                }
                if ((unsigned)(y0 + 1) < (unsigned)HH) {
                    const float* row = base + (size_t)(y0 + 1) * WW;
                    if ((unsigned)x0 < (unsigned)WW)       v10 = row[x0];
                    if ((unsigned)(x0 + 1) < (unsigned)WW) v11 = row[x0 + 1];
                }
            }
            float top = v00 + lx * (v01 - v00);
            float bot = v10 + lx * (v11 - v10);
            samp[t][c] = top + ly * (bot - top);
        }
        __syncthreads();

        // ---- compute: acc[t] += samp[t][c] * w[co][c][k] ----
        if (FAST) {
            const float* wk = wgt + (size_t)k * CIN * COUT + tid;
            for (int c = 0; c < CIN; c += 4) {
                float w0 = wk[(c + 0) * COUT];
                float w1 = wk[(c + 1) * COUT];
                float w2 = wk[(c + 2) * COUT];
                float w3 = wk[(c + 3) * COUT];
#pragma unroll
                for (int t = 0; t < TPOS; ++t) {
                    const float4 s = *(const float4*)&samp[t][c];
                    acc[t] = fmaf(s.x, w0, acc[t]);
                    acc[t] = fmaf(s.y, w1, acc[t]);
                    acc[t] = fmaf(s.z, w2, acc[t]);
                    acc[t] = fmaf(s.w, w3, acc[t]);
                }
            }
        } else {
            const float* wk = wgt + (size_t)tid * CIN * KK + k;
            for (int c = 0; c < CIN; c += 4) {
                float w0 = wk[(c + 0) * KK];
                float w1 = wk[(c + 1) * KK];
                float w2 = wk[(c + 2) * KK];
                float w3 = wk[(c + 3) * KK];
#pragma unroll
                for (int t = 0; t < TPOS; ++t) {
                    const float4 s = *(const float4*)&samp[t][c];
                    acc[t] = fmaf(s.x, w0, acc[t]);
                    acc[t] = fmaf(s.y, w1, acc[t]);
                    acc[t] = fmaf(s.z, w2, acc[t]);
                    acc[t] = fmaf(s.w, w3, acc[t]);
                }
            }
        }
    }

    // ---- write out[n][co][ho][wo0+t] ----
#pragma unroll
    for (int t = 0; t < TPOS; ++t)
        out[(((size_t)n * COUT + tid) * HO + ho) * WO + wo0 + t] = acc[t];
}

extern "C" void kernel_launch(void* const* d_in, const int* in_sizes, int n_in,
                              void* d_out, int out_size, void* d_ws, size_t ws_size,
                              hipStream_t stream) {
    const float* inp = (const float*)d_in[0];   // [8,128,96,96]
    const float* off = (const float*)d_in[1];   // [8,18,96,96]
    const float* wgt = (const float*)d_in[2];   // [256,128,3,3]
    float* out = (float*)d_out;                 // [8,256,96,96]

    const size_t img_bytes = (size_t)NN * HH * WW * CIN * sizeof(float);   // ~37.7 MB
    const size_t wt_bytes  = (size_t)KK * CIN * COUT * sizeof(float);      // ~1.2 MB
    const int n_blocks = (NN * HO * WO) / TPOS;                            // 9216

    if (ws_size >= img_bytes + wt_bytes) {
        float* img_nhwc = (float*)d_ws;
        float* wT       = (float*)((char*)d_ws + img_bytes);
        {
            int total = NN * HH * WW * CIN;
            nchw_to_nhwc<<<(total + 255) / 256, 256, 0, stream>>>(inp, img_nhwc);
        }
        {
            int total = KK * CIN * COUT;
            w_transpose<<<(total + 255) / 256, 256, 0, stream>>>(wgt, wT);
        }
        deform_main<true><<<n_blocks, 256, 0, stream>>>(img_nhwc, off, wT, out);
    } else {
        deform_main<false><<<n_blocks, 256, 0, stream>>>(inp, off, wgt, out);
    }
}

// Round 2
// 166.215 us; speedup vs baseline: 6.1508x; 6.1508x over previous
//
#include <hip/hip_runtime.h>
#include <hip/hip_bf16.h>

#define NN   8
#define CIN  128
#define HH   96
#define WW   96
#define COUT 256
#define KK   9      // 3x3
#define HO   96
#define WO   96
#define PTOT (NN*HO*WO)          // 73728
#define BM   64                  // positions per block
#define KTOT (CIN*KK)            // 1152
#define KSTEPS (KTOT/32)         // 36

typedef short bf16x8 __attribute__((ext_vector_type(8)));
typedef float f32x4  __attribute__((ext_vector_type(4)));

// ---------------------------------------------------------------------------
// helpers
// ---------------------------------------------------------------------------
__device__ __forceinline__ float blo(unsigned u) { return __uint_as_float(u << 16); }
__device__ __forceinline__ float bhi(unsigned u) { return __uint_as_float(u & 0xffff0000u); }
__device__ __forceinline__ unsigned pack_bf2(float a, float b) {
    unsigned ua = __float_as_uint(a); ua += 0x7fffu + ((ua >> 16) & 1u);
    unsigned ub = __float_as_uint(b); ub += 0x7fffu + ((ub >> 16) & 1u);
    return (ua >> 16) | (ub & 0xffff0000u);
}
__device__ __forceinline__ unsigned short f2b(float a) {
    unsigned ua = __float_as_uint(a); ua += 0x7fffu + ((ua >> 16) & 1u);
    return (unsigned short)(ua >> 16);
}

// ---------------------------------------------------------------------------
// Preprocess 1: input fp32 NCHW -> bf16 NHWC  (one block per (n,y) plane)
// ---------------------------------------------------------------------------
__global__ __launch_bounds__(256) void to_nhwc_bf16(const float* __restrict__ in,
                                                    unsigned short* __restrict__ outp) {
    __shared__ float tile[CIN * 97];          // stride 97: bank spread
    const int ny = blockIdx.x;                // n*96 + y
    const int n = ny / HH, y = ny - n * HH;
    const float* src = in + (size_t)n * CIN * HH * WW + (size_t)y * WW;
    for (int i = threadIdx.x; i < CIN * WW; i += 256) {
        int c = i / WW, x = i - c * WW;
        tile[c * 97 + x] = src[(size_t)c * HH * WW + x];
    }
    __syncthreads();
    unsigned* dst = (unsigned*)(outp + (size_t)ny * WW * CIN);   // (x, c) pairs
    for (int i = threadIdx.x; i < (WW * CIN) / 2; i += 256) {
        int c2 = (i & 63) * 2;
        int x  = i >> 6;
        dst[x * (CIN / 2) + (c2 >> 1)] = pack_bf2(tile[c2 * 97 + x], tile[(c2 + 1) * 97 + x]);
    }
}

// ---------------------------------------------------------------------------
// Preprocess 2: weight fp32 [Cout][Cin][9] -> bf16 fragment-packed
// wp[((ks*16+cb)*64+l)*8+j] = W[cb*16+(l&15)][ (ks*32+(l>>4)*8+j) % 128 ][ ... /128 ]
// K-order: kglob = tap*128 + cin
// ---------------------------------------------------------------------------
__global__ __launch_bounds__(256) void w_pack(const float* __restrict__ w,
                                              unsigned short* __restrict__ wp) {
    int idx = blockIdx.x * 256 + threadIdx.x;     // < 36*16*64*8 = 294912
    if (idx >= KSTEPS * 16 * 64 * 8) return;
    int j  = idx & 7;
    int l  = (idx >> 3) & 63;
    int cb = (idx >> 9) & 15;
    int ks = idx >> 13;
    int co  = cb * 16 + (l & 15);
    int kg  = ks * 32 + ((l >> 4) * 8) + j;
    int tap = kg >> 7;
    int cin = kg & 127;
    wp[idx] = f2b(w[((size_t)co * CIN + cin) * KK + tap]);
}

// ---------------------------------------------------------------------------
// Main: implicit GEMM with bf16 MFMA.
// Block: 256 thr = 4 waves. M-tile = 64 consecutive linear positions (fixed n).
// Wave w owns Cout range [w*64, w*64+64). K = 9 taps x 128 cin.
// ---------------------------------------------------------------------------
#define SMEM_BYTES 69632
#define SAMP_OFF   4608

__global__ __launch_bounds__(256, 2) void deform_mfma(
    const unsigned short* __restrict__ imgB,   // bf16 NHWC
    const float*          __restrict__ off,    // [N][18][96][96]
    const unsigned short* __restrict__ wPack,  // bf16 frag-packed
    float*                __restrict__ out)    // [N][256][96][96]
{
    __shared__ __align__(16) char smem[SMEM_BYTES];
    float* offL = (float*)smem;                       // [9][2][64] = 4608 B (py/px)

    const int t    = threadIdx.x;
    const int lane = t & 63;
    const int wv   = t >> 6;
    const int p0   = blockIdx.x * BM;
    const int nb   = p0 / (HO * WO);
    const int p0rem = p0 - nb * (HO * WO);

    // ---- stage offsets, pre-adding the base grid -> py/px per (tap, pos) ----
    for (int i = t; i < KK * 2 * BM; i += 256) {
        int m  = i & 63;
        int kd = i >> 6;              // 2*tap + d
        int k  = kd >> 1, d = kd & 1;
        int plin = p0rem + m;
        int ho = plin / WO, wo = plin - ho * WO;
        int kh = k / 3, kw = k - kh * 3;
        float base = d ? (float)(wo - 1 + kw) : (float)(ho - 1 + kh);
        offL[kd * 64 + m] = base + off[((size_t)nb * 2 * KK + kd) * (HO * WO) + plin];
    }

    f32x4 acc[4][4];
#pragma unroll
    for (int mf = 0; mf < 4; ++mf)
#pragma unroll
        for (int nf = 0; nf < 4; ++nf) acc[mf][nf] = (f32x4)0.f;

    const unsigned short* imgN = imgB + (size_t)nb * (HH * WW) * CIN;

    for (int tap = 0; tap < KK; ++tap) {
        __syncthreads();
        // ---- stage samp[64 pos][128 cin] bf16 into swizzled LDS ----
#pragma unroll
        for (int it = 0; it < 4; ++it) {
            int item  = t + it * 256;        // 0..1023
            int pos   = item >> 4;           // 0..63
            int chunk = item & 15;           // 8-cin chunk
            float py = offL[tap * 128 + pos];
            float px = offL[tap * 128 + 64 + pos];
            float y0f = floorf(py), x0f = floorf(px);
            float ly = py - y0f, lx = px - x0f;
            int y0 = (int)y0f, x0 = (int)x0f;
            float w11 = ly * lx;
            float w10 = ly - w11;            // ly*(1-lx)
            float w01 = lx - w11;            // (1-ly)*lx
            float w00 = 1.f - ly - lx + w11; // (1-ly)*(1-lx)

            uint4 z = {0u, 0u, 0u, 0u};
            uint4 r00 = z, r01 = z, r10 = z, r11 = z;
            bool xv0 = (unsigned)x0 < (unsigned)WW;
            bool xv1 = (unsigned)(x0 + 1) < (unsigned)WW;
            const unsigned short* bp = imgN + chunk * 8;
            if ((unsigned)y0 < (unsigned)HH) {
                const unsigned short* rp = bp + (size_t)(y0 * WW) * CIN;
                if (xv0) r00 = *(const uint4*)(rp + (size_t)x0 * CIN);
                if (xv1) r01 = *(const uint4*)(rp + (size_t)(x0 + 1) * CIN);
            }
            if ((unsigned)(y0 + 1) < (unsigned)HH) {
                const unsigned short* rp = bp + (size_t)((y0 + 1) * WW) * CIN;
                if (xv0) r10 = *(const uint4*)(rp + (size_t)x0 * CIN);
                if (xv1) r11 = *(const uint4*)(rp + (size_t)(x0 + 1) * CIN);
            }
            unsigned pk[4];
            {
                float s0, s1;
                s0 = blo(r00.x)*w00 + blo(r01.x)*w01 + blo(r10.x)*w10 + blo(r11.x)*w11;
                s1 = bhi(r00.x)*w00 + bhi(r01.x)*w01 + bhi(r10.x)*w10 + bhi(r11.x)*w11;
                pk[0] = pack_bf2(s0, s1);
                s0 = blo(r00.y)*w00 + blo(r01.y)*w01 + blo(r10.y)*w10 + blo(r11.y)*w11;
                s1 = bhi(r00.y)*w00 + bhi(r01.y)*w01 + bhi(r10.y)*w10 + bhi(r11.y)*w11;
                pk[1] = pack_bf2(s0, s1);
                s0 = blo(r00.z)*w00 + blo(r01.z)*w01 + blo(r10.z)*w10 + blo(r11.z)*w11;
                s1 = bhi(r00.z)*w00 + bhi(r01.z)*w01 + bhi(r10.z)*w10 + bhi(r11.z)*w11;
                pk[2] = pack_bf2(s0, s1);
                s0 = blo(r00.w)*w00 + blo(r01.w)*w01 + blo(r10.w)*w10 + blo(r11.w)*w11;
                s1 = bhi(r00.w)*w00 + bhi(r01.w)*w01 + bhi(r10.w)*w10 + bhi(r11.w)*w11;
                pk[3] = pack_bf2(s0, s1);
            }
            int byte = pos * 256 + chunk * 16;
            byte ^= (pos & 7) << 4;                       // T2 swizzle
            *(uint4*)(smem + SAMP_OFF + byte) = make_uint4(pk[0], pk[1], pk[2], pk[3]);
        }
        __syncthreads();

        // ---- 4 K-steps of MFMA ----
#pragma unroll
        for (int cs = 0; cs < 4; ++cs) {
            int ks = tap * 4 + cs;
            bf16x8 a[4], b[4];
#pragma unroll
            for (int mf = 0; mf < 4; ++mf) {
                int row  = mf * 16 + (lane & 15);
                int byte = row * 256 + cs * 64 + ((lane >> 4) * 16);
                byte ^= (row & 7) << 4;
                a[mf] = *(const bf16x8*)(smem + SAMP_OFF + byte);
            }
#pragma unroll
            for (int nf = 0; nf < 4; ++nf) {
                int tile = ks * 16 + (wv * 4 + nf);
                b[nf] = *(const bf16x8*)(wPack + (size_t)tile * 512 + lane * 8);
            }
#pragma unroll
            for (int mf = 0; mf < 4; ++mf)
#pragma unroll
                for (int nf = 0; nf < 4; ++nf)
                    acc[mf][nf] = __builtin_amdgcn_mfma_f32_16x16x32_bf16(
                        a[mf], b[nf], acc[mf][nf], 0, 0, 0);
        }
    }

    // ---- epilogue: per-wave LDS transpose -> coalesced row writes ----
    __syncthreads();
    float* cT = (float*)smem + wv * (64 * 68);            // [co 64][m 64] stride 68
#pragma unroll
    for (int nf = 0; nf < 4; ++nf) {
        int col = nf * 16 + (lane & 15);
#pragma unroll
        for (int mf = 0; mf < 4; ++mf) {
            int m0 = mf * 16 + ((lane >> 4) * 4);
            *(f32x4*)&cT[col * 68 + m0] = acc[mf][nf];
        }
    }
    asm volatile("s_waitcnt lgkmcnt(0)" ::: "memory");
    __builtin_amdgcn_sched_barrier(0);
    float* outp = out + ((size_t)nb * COUT + wv * 64 + lane) * (HO * WO) + p0rem;
#pragma unroll
    for (int m0 = 0; m0 < 64; m0 += 4) {
        f32x4 v = *(f32x4*)&cT[lane * 68 + m0];
        *(float4*)(outp + m0) = *(float4*)&v;
    }
}

// ---------------------------------------------------------------------------
// Fallback (fp32, no workspace) — correctness insurance if ws is too small.
// ---------------------------------------------------------------------------
__global__ __launch_bounds__(256) void deform_fallback(const float* __restrict__ img,
                                                       const float* __restrict__ off,
                                                       const float* __restrict__ wgt,
                                                       float* __restrict__ out) {
    __shared__ float samp[8][CIN];
    const int tid = threadIdx.x;
    const int p0  = blockIdx.x * 8;
    const int n   = p0 / (HO * WO);
    const int rem = p0 % (HO * WO);
    const int ho  = rem / WO;
    const int wo0 = rem % WO;
    float acc[8];
#pragma unroll
    for (int t = 0; t < 8; ++t) acc[t] = 0.f;
    for (int k = 0; k < KK; ++k) {
        __syncthreads();
        const int kh = k / 3, kw = k % 3;
#pragma unroll
        for (int it = 0; it < 4; ++it) {
            int idx = tid + it * 256;
            int t   = idx >> 7;
            int c   = idx & (CIN - 1);
            int wo  = wo0 + t;
            float dy = off[(((size_t)n * 2 * KK + 2 * k) * HO + ho) * WO + wo];
            float dx = off[(((size_t)n * 2 * KK + 2 * k + 1) * HO + ho) * WO + wo];
            float py = (float)(ho - 1 + kh) + dy;
            float px = (float)(wo - 1 + kw) + dx;
            float y0f = floorf(py), x0f = floorf(px);
            float ly = py - y0f, lx = px - x0f;
            int y0 = (int)y0f, x0 = (int)x0f;
            float v00 = 0.f, v01 = 0.f, v10 = 0.f, v11 = 0.f;
            const float* base = img + ((size_t)n * CIN + c) * HH * WW;
            if ((unsigned)y0 < (unsigned)HH) {
                const float* row = base + (size_t)y0 * WW;
                if ((unsigned)x0 < (unsigned)WW)       v00 = row[x0];
                if ((unsigned)(x0 + 1) < (unsigned)WW) v01 = row[x0 + 1];
            }
            if ((unsigned)(y0 + 1) < (unsigned)HH) {
                const float* row = base + (size_t)(y0 + 1) * WW;
                if ((unsigned)x0 < (unsigned)WW)       v10 = row[x0];
                if ((unsigned)(x0 + 1) < (unsigned)WW) v11 = row[x0 + 1];
            }
            float top = v00 + lx * (v01 - v00);
            float bot = v10 + lx * (v11 - v10);
            samp[t][c] = top + ly * (bot - top);
        }
        __syncthreads();
        const float* wk = wgt + (size_t)tid * CIN * KK + k;
        for (int c = 0; c < CIN; c += 4) {
            float w0 = wk[(c + 0) * KK], w1 = wk[(c + 1) * KK];
            float w2 = wk[(c + 2) * KK], w3 = wk[(c + 3) * KK];
#pragma unroll
            for (int t = 0; t < 8; ++t) {
                const float4 s = *(const float4*)&samp[t][c];
                acc[t] = fmaf(s.x, w0, acc[t]);
                acc[t] = fmaf(s.y, w1, acc[t]);
                acc[t] = fmaf(s.z, w2, acc[t]);
                acc[t] = fmaf(s.w, w3, acc[t]);
            }
        }
    }
#pragma unroll
    for (int t = 0; t < 8; ++t)
        out[(((size_t)n * COUT + tid) * HO + ho) * WO + wo0 + t] = acc[t];
}

extern "C" void kernel_launch(void* const* d_in, const int* in_sizes, int n_in,
                              void* d_out, int out_size, void* d_ws, size_t ws_size,
                              hipStream_t stream) {
    const float* inp = (const float*)d_in[0];
    const float* off = (const float*)d_in[1];
    const float* wgt = (const float*)d_in[2];
    float* out = (float*)d_out;

    const size_t img_bytes = (size_t)NN * HH * WW * CIN * 2;          // 18,874,368
    const size_t wp_bytes  = (size_t)KSTEPS * 16 * 64 * 8 * 2;        // 589,824

    if (ws_size >= img_bytes + wp_bytes) {
        unsigned short* imgB  = (unsigned short*)d_ws;
        unsigned short* wPack = (unsigned short*)((char*)d_ws + img_bytes);
        to_nhwc_bf16<<<NN * HH, 256, 0, stream>>>(inp, imgB);
        w_pack<<<(KSTEPS * 16 * 64 * 8) / 256, 256, 0, stream>>>(wgt, wPack);
        deform_mfma<<<PTOT / BM, 256, 0, stream>>>(imgB, off, wPack, out);
    } else {
        deform_fallback<<<PTOT / 8, 256, 0, stream>>>(inp, off, wgt, out);
    }
}

// Round 3
// 144.360 us; speedup vs baseline: 7.0820x; 1.1514x over previous
//
#include <hip/hip_runtime.h>
#include <hip/hip_bf16.h>

#define NN   8
#define CIN  128
#define HH   96
#define WW   96
#define COUT 256
#define KK   9      // 3x3
#define HO   96
#define WO   96
#define PTOT (NN*HO*WO)          // 73728
#define BM   64                  // positions per block
#define KTOT (CIN*KK)            // 1152
#define KSTEPS (KTOT/32)         // 36

typedef short bf16x8 __attribute__((ext_vector_type(8)));
typedef float f32x4  __attribute__((ext_vector_type(4)));
typedef float f32x2  __attribute__((ext_vector_type(2)));

// ---------------------------------------------------------------------------
// helpers
// ---------------------------------------------------------------------------
__device__ __forceinline__ f32x2 unpk(unsigned u) {
    f32x2 r;
    r.x = __uint_as_float(u << 16);
    r.y = __uint_as_float(u & 0xffff0000u);
    return r;
}
__device__ __forceinline__ unsigned pack_bf2(float a, float b) {
    unsigned ua = __float_as_uint(a); ua += 0x7fffu + ((ua >> 16) & 1u);
    unsigned ub = __float_as_uint(b); ub += 0x7fffu + ((ub >> 16) & 1u);
    return (ua >> 16) | (ub & 0xffff0000u);
}
__device__ __forceinline__ unsigned short f2b(float a) {
    unsigned ua = __float_as_uint(a); ua += 0x7fffu + ((ua >> 16) & 1u);
    return (unsigned short)(ua >> 16);
}

// ---------------------------------------------------------------------------
// Preprocess 1: input fp32 NCHW -> bf16 NHWC  (one block per (n,y) plane)
// ---------------------------------------------------------------------------
__global__ __launch_bounds__(256) void to_nhwc_bf16(const float* __restrict__ in,
                                                    unsigned short* __restrict__ outp) {
    __shared__ float tile[CIN * 97];
    const int ny = blockIdx.x;                // n*96 + y
    const int n = ny / HH, y = ny - n * HH;
    const float* src = in + (size_t)n * CIN * HH * WW + (size_t)y * WW;
    for (int i = threadIdx.x; i < CIN * WW; i += 256) {
        int c = i / WW, x = i - c * WW;
        tile[c * 97 + x] = src[(size_t)c * HH * WW + x];
    }
    __syncthreads();
    unsigned* dst = (unsigned*)(outp + (size_t)ny * WW * CIN);
    for (int i = threadIdx.x; i < (WW * CIN) / 2; i += 256) {
        int c2 = (i & 63) * 2;
        int x  = i >> 6;
        dst[x * (CIN / 2) + (c2 >> 1)] = pack_bf2(tile[c2 * 97 + x], tile[(c2 + 1) * 97 + x]);
    }
}

// ---------------------------------------------------------------------------
// Preprocess 2: weight fp32 [Cout][Cin][9] -> bf16 fragment-packed
// ---------------------------------------------------------------------------
__global__ __launch_bounds__(256) void w_pack(const float* __restrict__ w,
                                              unsigned short* __restrict__ wp) {
    int idx = blockIdx.x * 256 + threadIdx.x;
    if (idx >= KSTEPS * 16 * 64 * 8) return;
    int j  = idx & 7;
    int l  = (idx >> 3) & 63;
    int cb = (idx >> 9) & 15;
    int ks = idx >> 13;
    int co  = cb * 16 + (l & 15);
    int kg  = ks * 32 + ((l >> 4) * 8) + j;
    int tap = kg >> 7;
    int cin = kg & 127;
    wp[idx] = f2b(w[((size_t)co * CIN + cin) * KK + tap]);
}

// ---------------------------------------------------------------------------
// Main: implicit GEMM, double-buffered gather, one barrier per tap.
// LDS: offL [0,4608) | buf0 [4608,20992) | buf1 [20992,37376)
// Epilogue reuses [0,20480) as per-wave transpose tiles.
// ---------------------------------------------------------------------------
#define LDS_BYTES 37376
#define BUF0 4608
#define BUF1 20992

__global__ __launch_bounds__(256, 4) void deform_mfma(
    const unsigned short* __restrict__ imgB,   // bf16 NHWC
    const float*          __restrict__ off,    // [N][18][96][96]
    const unsigned short* __restrict__ wPack,  // bf16 frag-packed
    float*                __restrict__ out)    // [N][256][96][96]
{
    __shared__ __align__(16) char smem[LDS_BYTES];
    float* offL = (float*)smem;                       // [9][2][64] py/px

    const int t    = threadIdx.x;
    const int lane = t & 63;
    const int wv   = t >> 6;
    const int p0   = blockIdx.x * BM;
    const int nb   = p0 / (HO * WO);
    const int p0rem = p0 - nb * (HO * WO);

    // ---- stage offsets, pre-adding the base grid -> py/px per (tap, pos) ----
    for (int i = t; i < KK * 2 * BM; i += 256) {
        int m  = i & 63;
        int kd = i >> 6;              // 2*tap + d
        int k  = kd >> 1, d = kd & 1;
        int plin = p0rem + m;
        int ho = plin / WO, wo = plin - ho * WO;
        int kh = k / 3, kw = k - kh * 3;
        float base = d ? (float)(wo - 1 + kw) : (float)(ho - 1 + kh);
        offL[kd * 64 + m] = base + off[((size_t)nb * 2 * KK + kd) * (HO * WO) + plin];
    }

    f32x4 acc[4][4];
#pragma unroll
    for (int mf = 0; mf < 4; ++mf)
#pragma unroll
        for (int nf = 0; nf < 4; ++nf) acc[mf][nf] = (f32x4)0.f;

    const unsigned short* imgN = imgB + (size_t)nb * (HH * WW) * CIN;

    // branchless bilinear gather of samp[64 pos][128 cin] for one tap
    auto gather = [&](int tap, char* bufw) {
#pragma unroll
        for (int it = 0; it < 4; ++it) {
            int item  = t + it * 256;        // 0..1023
            int pos   = item >> 4;           // 0..63
            int chunk = item & 15;           // 8-cin chunk
            float py = offL[(2 * tap) * 64 + pos];
            float px = offL[(2 * tap + 1) * 64 + pos];
            float y0f = floorf(py), x0f = floorf(px);
            float ly = py - y0f, lx = px - x0f;
            int y0 = (int)y0f, x0 = (int)x0f;

            bool vy0 = (unsigned)y0 < (unsigned)HH;
            bool vy1 = (unsigned)(y0 + 1) < (unsigned)HH;
            bool vx0 = (unsigned)x0 < (unsigned)WW;
            bool vx1 = (unsigned)(x0 + 1) < (unsigned)WW;
            int yc0 = min(max(y0, 0), HH - 1);
            int yc1 = min(max(y0 + 1, 0), HH - 1);
            int xc0 = min(max(x0, 0), WW - 1);
            int xc1 = min(max(x0 + 1, 0), WW - 1);

            float w11 = ly * lx;
            float w10 = ly - w11;
            float w01 = lx - w11;
            float w00 = 1.f - ly - lx + w11;
            w00 = (vy0 && vx0) ? w00 : 0.f;
            w01 = (vy0 && vx1) ? w01 : 0.f;
            w10 = (vy1 && vx0) ? w10 : 0.f;
            w11 = (vy1 && vx1) ? w11 : 0.f;

            const unsigned short* pch = imgN + chunk * 8;
            const unsigned short* r0p = pch + (size_t)(yc0 * WW) * CIN;
            const unsigned short* r1p = pch + (size_t)(yc1 * WW) * CIN;
            uint4 r00 = *(const uint4*)(r0p + (size_t)xc0 * CIN);
            uint4 r01 = *(const uint4*)(r0p + (size_t)xc1 * CIN);
            uint4 r10 = *(const uint4*)(r1p + (size_t)xc0 * CIN);
            uint4 r11 = *(const uint4*)(r1p + (size_t)xc1 * CIN);

            unsigned pk[4];
            f32x2 s;
            s = unpk(r00.x) * w00 + unpk(r01.x) * w01 + unpk(r10.x) * w10 + unpk(r11.x) * w11;
            pk[0] = pack_bf2(s.x, s.y);
            s = unpk(r00.y) * w00 + unpk(r01.y) * w01 + unpk(r10.y) * w10 + unpk(r11.y) * w11;
            pk[1] = pack_bf2(s.x, s.y);
            s = unpk(r00.z) * w00 + unpk(r01.z) * w01 + unpk(r10.z) * w10 + unpk(r11.z) * w11;
            pk[2] = pack_bf2(s.x, s.y);
            s = unpk(r00.w) * w00 + unpk(r01.w) * w01 + unpk(r10.w) * w10 + unpk(r11.w) * w11;
            pk[3] = pack_bf2(s.x, s.y);

            int byte = pos * 256 + chunk * 16;
            byte ^= (pos & 7) << 4;                       // T2 swizzle
            *(uint4*)(bufw + byte) = make_uint4(pk[0], pk[1], pk[2], pk[3]);
        }
    };

    __syncthreads();                 // offL visible
    gather(0, smem + BUF0);

    for (int tap = 0; tap < KK; ++tap) {
        __syncthreads();             // buf[tap&1] fully written
        const char* bufr = smem + ((tap & 1) ? BUF1 : BUF0);

        // ---- 4 K-steps of MFMA on buf[tap&1] ----
#pragma unroll
        for (int cs = 0; cs < 4; ++cs) {
            int ks = tap * 4 + cs;
            bf16x8 a[4], b[4];
#pragma unroll
            for (int mf = 0; mf < 4; ++mf) {
                int row  = mf * 16 + (lane & 15);
                int byte = row * 256 + cs * 64 + ((lane >> 4) * 16);
                byte ^= (row & 7) << 4;
                a[mf] = *(const bf16x8*)(bufr + byte);
            }
#pragma unroll
            for (int nf = 0; nf < 4; ++nf) {
                int tile = ks * 16 + (wv * 4 + nf);
                b[nf] = *(const bf16x8*)(wPack + (size_t)tile * 512 + lane * 8);
            }
#pragma unroll
            for (int mf = 0; mf < 4; ++mf)
#pragma unroll
                for (int nf = 0; nf < 4; ++nf)
                    acc[mf][nf] = __builtin_amdgcn_mfma_f32_16x16x32_bf16(
                        a[mf], b[nf], acc[mf][nf], 0, 0, 0);
        }

        // ---- overlap: gather next tap into the other buffer ----
        if (tap + 1 < KK) gather(tap + 1, smem + ((tap & 1) ? BUF0 : BUF1));
    }

    // ---- epilogue: per-wave, per-mf LDS transpose -> coalesced row writes ----
    __syncthreads();
    float* cT = (float*)smem + wv * (64 * 20);            // 5120 B per wave
    const int colbase = lane & 15;
    const int rowq    = lane >> 4;                        // 0..3
    float* outbase = out + ((size_t)nb * COUT + wv * 64 + lane) * (HO * WO) + p0rem;
#pragma unroll
    for (int mf = 0; mf < 4; ++mf) {
#pragma unroll
        for (int nf = 0; nf < 4; ++nf) {
            int co = nf * 16 + colbase;
            *(f32x4*)&cT[co * 20 + rowq * 4] = acc[mf][nf];
        }
        asm volatile("s_waitcnt lgkmcnt(0)" ::: "memory");
        __builtin_amdgcn_sched_barrier(0);
#pragma unroll
        for (int q = 0; q < 4; ++q) {
            f32x4 v = *(f32x4*)&cT[lane * 20 + q * 4];
            *(float4*)(outbase + mf * 16 + q * 4) = *(float4*)&v;
        }
    }
}

// ---------------------------------------------------------------------------
// Fallback (fp32, no workspace) — correctness insurance if ws is too small.
// ---------------------------------------------------------------------------
__global__ __launch_bounds__(256) void deform_fallback(const float* __restrict__ img,
                                                       const float* __restrict__ off,
                                                       const float* __restrict__ wgt,
                                                       float* __restrict__ out) {
    __shared__ float samp[8][CIN];
    const int tid = threadIdx.x;
    const int p0  = blockIdx.x * 8;
    const int n   = p0 / (HO * WO);
    const int rem = p0 % (HO * WO);
    const int ho  = rem / WO;
    const int wo0 = rem % WO;
    float acc[8];
#pragma unroll
    for (int t = 0; t < 8; ++t) acc[t] = 0.f;
    for (int k = 0; k < KK; ++k) {
        __syncthreads();
        const int kh = k / 3, kw = k % 3;
#pragma unroll
        for (int it = 0; it < 4; ++it) {
            int idx = tid + it * 256;
            int t   = idx >> 7;
            int c   = idx & (CIN - 1);
            int wo  = wo0 + t;
            float dy = off[(((size_t)n * 2 * KK + 2 * k) * HO + ho) * WO + wo];
            float dx = off[(((size_t)n * 2 * KK + 2 * k + 1) * HO + ho) * WO + wo];
            float py = (float)(ho - 1 + kh) + dy;
            float px = (float)(wo - 1 + kw) + dx;
            float y0f = floorf(py), x0f = floorf(px);
            float ly = py - y0f, lx = px - x0f;
            int y0 = (int)y0f, x0 = (int)x0f;
            float v00 = 0.f, v01 = 0.f, v10 = 0.f, v11 = 0.f;
            const float* base = img + ((size_t)n * CIN + c) * HH * WW;
            if ((unsigned)y0 < (unsigned)HH) {
                const float* row = base + (size_t)y0 * WW;
                if ((unsigned)x0 < (unsigned)WW)       v00 = row[x0];
                if ((unsigned)(x0 + 1) < (unsigned)WW) v01 = row[x0 + 1];
            }
            if ((unsigned)(y0 + 1) < (unsigned)HH) {
                const float* row = base + (size_t)(y0 + 1) * WW;
                if ((unsigned)x0 < (unsigned)WW)       v10 = row[x0];
                if ((unsigned)(x0 + 1) < (unsigned)WW) v11 = row[x0 + 1];
            }
            float top = v00 + lx * (v01 - v00);
            float bot = v10 + lx * (v11 - v10);
            samp[t][c] = top + ly * (bot - top);
        }
        __syncthreads();
        const float* wk = wgt + (size_t)tid * CIN * KK + k;
        for (int c = 0; c < CIN; c += 4) {
            float w0 = wk[(c + 0) * KK], w1 = wk[(c + 1) * KK];
            float w2 = wk[(c + 2) * KK], w3 = wk[(c + 3) * KK];
#pragma unroll
            for (int t = 0; t < 8; ++t) {
                const float4 s = *(const float4*)&samp[t][c];
                acc[t] = fmaf(s.x, w0, acc[t]);
                acc[t] = fmaf(s.y, w1, acc[t]);
                acc[t] = fmaf(s.z, w2, acc[t]);
                acc[t] = fmaf(s.w, w3, acc[t]);
            }
        }
    }
#pragma unroll
    for (int t = 0; t < 8; ++t)
        out[(((size_t)n * COUT + tid) * HO + ho) * WO + wo0 + t] = acc[t];
}

extern "C" void kernel_launch(void* const* d_in, const int* in_sizes, int n_in,
                              void* d_out, int out_size, void* d_ws, size_t ws_size,
                              hipStream_t stream) {
    const float* inp = (const float*)d_in[0];
    const float* off = (const float*)d_in[1];
    const float* wgt = (const float*)d_in[2];
    float* out = (float*)d_out;

    const size_t img_bytes = (size_t)NN * HH * WW * CIN * 2;
    const size_t wp_bytes  = (size_t)KSTEPS * 16 * 64 * 8 * 2;

    if (ws_size >= img_bytes + wp_bytes) {
        unsigned short* imgB  = (unsigned short*)d_ws;
        unsigned short* wPack = (unsigned short*)((char*)d_ws + img_bytes);
        to_nhwc_bf16<<<NN * HH, 256, 0, stream>>>(inp, imgB);
        w_pack<<<(KSTEPS * 16 * 64 * 8) / 256, 256, 0, stream>>>(wgt, wPack);
        deform_mfma<<<PTOT / BM, 256, 0, stream>>>(imgB, off, wPack, out);
    } else {
        deform_fallback<<<PTOT / 8, 256, 0, stream>>>(inp, off, wgt, out);
    }
}